// Round 1
// 723.678 us; speedup vs baseline: 1.0054x; 1.0054x over previous
//
#include <hip/hip_runtime.h>
#include <math.h>

#define K 8192
#define BROWS 4096
#define ALPHA 0.5f
#define NTOT ((size_t)K * (size_t)K)   // 67108864
#define VEC4 16777215                  // (NTOT - 3 - 1) / 4 aligned float4 stores

__device__ __forceinline__ void argmax_combine(float& v, int& i, float v2, int i2){
  if (v2 > v || (v2 == v && i2 < i)) { v = v2; i = i2; }
}

// K1: fused row-stats (4096 virtual blocks) + S_t -> out_St copy (8192 virtual
// blocks), interleaved 1:2 so each CU holds a mix of dependency-phased row
// blocks and pure-streaming copy blocks. The copy soaks HBM bandwidth left
// idle during the row blocks' shuffle/sync/exp phases.
//
// Copy vectorization: out_St = out+1 is only 4B-aligned, but out+4 is
// 16B-aligned. Store float4 to out[4+4d..7+4d] = S_t[3+4d..6+4d]; the source
// reads compile to dword + dwordx3 (both aligned). Head (3 elems) and tail
// (1 elem) are scalar in copy-block 0.
__global__ __launch_bounds__(256) void fused_kernel(
    const float* __restrict__ outputs,
    const float* __restrict__ targets,
    const float* __restrict__ S,
    const float* __restrict__ S_t,
    const float* __restrict__ count,
    float* __restrict__ out,
    float* __restrict__ rowloss,
    int*   __restrict__ rowtl,
    int*   __restrict__ rowcorrect,
    float* __restrict__ rowm,
    float* __restrict__ rowinvZ)
{
  __shared__ float s_v[2][4]; __shared__ int s_i[2][4];
  __shared__ float s_m; __shared__ int s_pred; __shared__ int s_tl;
  __shared__ float s_sums[4][5];

  const int bb = blockIdx.x;
  const int r  = bb / 3;          // 0..4095
  const int m3 = bb - r * 3;      // 0,1,2
  const int t  = threadIdx.x;
  const int lane = t & 63;
  const int wid  = t >> 6;

  if (m3 != 0) {
    // ---------------- copy path ----------------
    const int cb = 2 * r + (m3 - 1);              // 0..8191
    float4* dst4 = (float4*)(out + 4);            // 16B-aligned
    const size_t base = (size_t)cb * 2048 + t;
    if (cb != 8191) {
#pragma unroll
      for (int i = 0; i < 8; ++i) {
        size_t d = base + (size_t)i * 256;
        size_t e = 4 * d + 3;
        float4 v; v.x = S_t[e]; v.y = S_t[e+1]; v.z = S_t[e+2]; v.w = S_t[e+3];
        dst4[d] = v;
      }
    } else {
      // last virtual copy block: one slot (d == VEC4) is out of range
#pragma unroll
      for (int i = 0; i < 8; ++i) {
        size_t d = base + (size_t)i * 256;
        if (d < (size_t)VEC4) {
          size_t e = 4 * d + 3;
          float4 v; v.x = S_t[e]; v.y = S_t[e+1]; v.z = S_t[e+2]; v.w = S_t[e+3];
          dst4[d] = v;
        }
      }
    }
    if (cb == 0) {
      if (t < 3) out[1 + t] = S_t[t];             // head: out[1..3]
      if (t == 3) out[NTOT] = S_t[NTOT - 1];      // tail: last S_t element
    } else if (cb == 1) {
      // count copy lives here (NOT in the epilogue) so the epilogue's
      // atomicAdd on out_count can't race with a plain store.
      float* out_count = out + 1 + NTOT;
      for (int i = t; i < K; i += 256) out_count[i] = count[i];
    }
    return;
  }

  // ---------------- row path (row r) ----------------
  const float4* orow = (const float4*)(outputs + (size_t)r * K);
  float x[32];
#pragma unroll
  for (int i = 0; i < 8; ++i){
    float4 v = orow[i*256 + t];
    x[4*i+0]=v.x; x[4*i+1]=v.y; x[4*i+2]=v.z; x[4*i+3]=v.w;
  }

  // local argmax over outputs (first-occurrence tie-break via index compare)
  float mv = -INFINITY; int mi = 0x7fffffff;
#pragma unroll
  for (int i = 0; i < 8; ++i){
#pragma unroll
    for (int c = 0; c < 4; ++c){
      int idx = i*1024 + t*4 + c;
      argmax_combine(mv, mi, x[4*i+c], idx);
    }
  }

  // targets pass: argmax(targets) -> tl, plus generic hard-CE partial dots
  const float4* trow = (const float4*)(targets + (size_t)r * K);
  float tv = -INFINITY; int ti = 0x7fffffff;
  float d_hard = 0.f, s_hard = 0.f;
#pragma unroll
  for (int i = 0; i < 8; ++i){
    float4 v = trow[i*256 + t];
    float tc[4] = {v.x, v.y, v.z, v.w};
#pragma unroll
    for (int c = 0; c < 4; ++c){
      int idx = i*1024 + t*4 + c;
      d_hard += x[4*i+c] * tc[c];
      s_hard += tc[c];
      argmax_combine(tv, ti, tc[c], idx);
    }
  }

  // wave-level argmax reductions (both pairs together)
#pragma unroll
  for (int off = 32; off; off >>= 1){
    float v2 = __shfl_down(mv, off, 64); int i2 = __shfl_down(mi, off, 64);
    argmax_combine(mv, mi, v2, i2);
    v2 = __shfl_down(tv, off, 64); i2 = __shfl_down(ti, off, 64);
    argmax_combine(tv, ti, v2, i2);
  }

  if (lane == 0){ s_v[0][wid]=mv; s_i[0][wid]=mi; s_v[1][wid]=tv; s_i[1][wid]=ti; }
  __syncthreads();
  if (t == 0){
    float av=s_v[0][0]; int ai=s_i[0][0];
    float bv=s_v[1][0]; int bi=s_i[1][0];
#pragma unroll
    for (int w=1; w<4; ++w){
      argmax_combine(av, ai, s_v[0][w], s_i[0][w]);
      argmax_combine(bv, bi, s_v[1][w], s_i[1][w]);
    }
    s_m = av; s_pred = ai; s_tl = bi;
  }
  __syncthreads();
  const float m  = s_m;
  const int   tl = s_tl;

  // sum exp(x - m) from registers
  float se = 0.f;
#pragma unroll
  for (int i = 0; i < 32; ++i) se += expf(x[i] - m);

  // soft-CE dot against S[tl] row
  const float4* srow = (const float4*)(S + (size_t)tl * K);
  float d_soft = 0.f, s_soft = 0.f;
#pragma unroll
  for (int i = 0; i < 8; ++i){
    float4 v = srow[i*256 + t];
    d_soft += x[4*i+0]*v.x + x[4*i+1]*v.y + x[4*i+2]*v.z + x[4*i+3]*v.w;
    s_soft += v.x + v.y + v.z + v.w;
  }

  // block-reduce the 5 sums
  float sums[5] = {d_hard, s_hard, se, d_soft, s_soft};
#pragma unroll
  for (int off = 32; off; off >>= 1){
#pragma unroll
    for (int j = 0; j < 5; ++j) sums[j] += __shfl_down(sums[j], off, 64);
  }
  if (lane == 0){
#pragma unroll
    for (int j = 0; j < 5; ++j) s_sums[wid][j] = sums[j];
  }
  __syncthreads();
  if (t == 0){
    float tot[5];
#pragma unroll
    for (int j=0;j<5;++j) tot[j] = s_sums[0][j]+s_sums[1][j]+s_sums[2][j]+s_sums[3][j];
    float Z = tot[2];
    float logZ = logf(Z);
    // sum(ls * w) = d - (m + logZ) * s   where ls = x - m - logZ
    float ceh = -(tot[0] - (m + logZ) * tot[1]);
    float ces = -(tot[3] - (m + logZ) * tot[4]);
    rowloss[r]    = (ALPHA * ceh + (1.0f - ALPHA) * ces) * (1.0f / (float)BROWS);
    rowtl[r]      = tl;
    rowcorrect[r] = (s_pred == tl) ? 1 : 0;
    rowm[r]       = m;
    rowinvZ[r]    = 1.0f / Z;
  }
}

// K2: epilogue. Block BROWS: deterministic loss reduction. Blocks [0,BROWS):
// scatter probs for correct rows (expected ~0-2 of 4096; early exit otherwise).
// atomicAdd handles multiple correct rows sharing a label. count was already
// copied in K1, so the count atomicAdd here is ordered after it by the kernel
// boundary.
__global__ __launch_bounds__(256) void epilogue_kernel(
    const float* __restrict__ outputs,
    const float* __restrict__ rowloss,
    const int*   __restrict__ rowtl,
    const int*   __restrict__ rowcorrect,
    const float* __restrict__ rowm,
    const float* __restrict__ rowinvZ,
    float* __restrict__ out)
{
  const int b = blockIdx.x;
  const int t = threadIdx.x;
  if (b == BROWS) {
    float s = 0.f;
    for (int i = t; i < BROWS; i += 256) s += rowloss[i];
#pragma unroll
    for (int off = 32; off; off >>= 1) s += __shfl_down(s, off, 64);
    __shared__ float sh[4];
    if ((t & 63) == 0) sh[t >> 6] = s;
    __syncthreads();
    if (t == 0) out[0] = sh[0] + sh[1] + sh[2] + sh[3];
    return;
  }
  if (!rowcorrect[b]) return;
  const int tl = rowtl[b];
  const float m = rowm[b], invZ = rowinvZ[b];
  const float* orow = outputs + (size_t)b * K;
  float* drow = out + 1 + (size_t)tl * K;
  for (int k = t; k < K; k += 256)
    atomicAdd(&drow[k], expf(orow[k] - m) * invZ);
  if (t == 0) atomicAdd(out + 1 + NTOT + tl, 1.0f);
}

extern "C" void kernel_launch(void* const* d_in, const int* in_sizes, int n_in,
                              void* d_out, int out_size, void* d_ws, size_t ws_size,
                              hipStream_t stream) {
  const float* outputs = (const float*)d_in[0];
  const float* targets = (const float*)d_in[1];
  const float* S       = (const float*)d_in[2];
  const float* S_t     = (const float*)d_in[3];
  const float* count   = (const float*)d_in[4];

  float* out = (float*)d_out;

  float* rowloss    = (float*)d_ws;            // B floats
  float* rowm       = rowloss + BROWS;         // B floats
  float* rowinvZ    = rowm + BROWS;            // B floats
  int*   rowtl      = (int*)(rowinvZ + BROWS); // B ints
  int*   rowcorrect = rowtl + BROWS;           // B ints

  hipLaunchKernelGGL(fused_kernel, dim3(3 * BROWS), dim3(256), 0, stream,
                     outputs, targets, S, S_t, count, out,
                     rowloss, rowtl, rowcorrect, rowm, rowinvZ);
  hipLaunchKernelGGL(epilogue_kernel, dim3(BROWS + 1), dim3(256), 0, stream,
                     outputs, rowloss, rowtl, rowcorrect, rowm, rowinvZ, out);
}